// Round 19
// baseline (151.673 us; speedup 1.0000x reference)
//
#include <hip/hip_runtime.h>
#include <hip/hip_fp16.h>
#include <math.h>

#define HH 56
#define WW 56
#define CC 64
#define BB 4
#define HWA (HH*WW)   // 3136

typedef _Float16 half8_t __attribute__((ext_vector_type(8)));
typedef _Float16 h2_t   __attribute__((ext_vector_type(2)));
typedef float f32x4_t __attribute__((ext_vector_type(4)));

// pair layout (padded): xp[b][y 0..56][j 0..56][c] = {v(y,j-1), v(y,j)} fp16.
// Row 56 is never written (poison = finite fp16); reads of it always carry 0 weight.
#define PROWS 57
#define PSTRB (PROWS*57*64*4)    // bytes per batch
#define ROWSTRB (57*64*4)        // bytes per row

// ---------- 1. fused prep: pair rows + conv fp16 layout + weight pack ----------
__global__ __launch_bounds__(256)
void k_prep(const float* __restrict__ x,
            const float* __restrict__ w3, const float* __restrict__ w2,
            const float* __restrict__ b3, const float* __restrict__ b2,
            __half2* __restrict__ xp, _Float16* __restrict__ xh,
            _Float16* __restrict__ Wp, float* __restrict__ bbp) {
    int blk = blockIdx.x;
    int tid = threadIdx.x;
    if (blk < BB*56) {
        __shared__ float ld[64*57];        // [c][xcol] pad 57
        int b = blk / 56, y = blk % 56;
        for (int i = tid; i < 64*56; i += 256) {
            int c = i / 56, col = i % 56;
            ld[c*57 + col] = x[((size_t)b*CC + c)*HWA + y*WW + col];
        }
        __syncthreads();
        for (int i = tid; i < 57*64; i += 256) {
            int j = i >> 6, c = i & 63;
            float lo = (j > 0)  ? ld[c*57 + j - 1] : 0.f;
            float hi = (j < 56) ? ld[c*57 + j]     : 0.f;
            xp[((size_t)(b*PROWS + y)*57 + j)*CC + c] = __floats2half2_rn(lo, hi);
        }
        _Float16* dst = xh + (((size_t)(b*2)*56 + y)*58)*32;
        for (int i = tid; i < 2*58*32; i += 256) {
            int g = i / 1856;
            int r = i % 1856;
            int col = r / 32, ic = r % 32;
            float v = 0.f;
            if (col >= 1 && col <= 56) v = ld[(g*32 + ic)*57 + col - 1];
            dst[(size_t)g*56*58*32 + r] = (_Float16)v;
        }
    } else {
        int i = (blk - BB*56)*256 + tid;
        if (i < 46080) {
            int j    = i & 7;
            int lane = (i >> 3) & 63;
            int mt   = (i >> 9) % 5;
            int kt   = (i / 2560) % 9;
            int g    = i / 23040;
            int m  = mt*16 + (lane & 15);
            int ic = (lane >> 4)*8 + j;
            int ky = kt/3, kx = kt%3;
            float v = 0.f;
            if (m < 49)      v = w3[((g*49 + m)*32 + ic)*9 + ky*3 + kx];
            else if (m < 74) v = w2[((g*25 + (m-49))*32 + ic)*9 + ky*3 + kx];
            Wp[i] = (_Float16)v;
        } else if (i < 46240) {
            int t = i - 46080; int g = t/80, m = t%80;
            float v = 0.f;
            if (m < 49)      v = b3[g*49 + m];
            else if (m < 74) v = b2[g*25 + (m-49)];
            bbp[t] = v;
        }
    }
}

// ---------- 2. MFMA conv: 4 waves/block, one 16-pixel tile per wave ----------
__global__ __launch_bounds__(256)
void k_convmfma(const _Float16* __restrict__ xh, const _Float16* __restrict__ Wp,
                const float* __restrict__ bb,
                float* __restrict__ off3, float* __restrict__ off2) {
    __shared__ _Float16 tile[4][3*18*32];   // 13824 B
    int blk = blockIdx.x;                   // 448
    int iy = blk % 56;
    int g  = (blk / 56) & 1;
    int b  = blk / 112;
    int wv   = threadIdx.y;                 // 0..3 = nq
    int lane = threadIdx.x;
    int n0 = wv * 16;

    const unsigned int* xs = (const unsigned int*)xh;
    unsigned int* tl = (unsigned int*)&tile[wv][0];
#pragma unroll
    for (int i = 0; i < 14; ++i) {
        int idx = i*64 + lane;              // 864 uints
        if (idx < 864) {
            int ic2 = idx & 15;
            int seg = idx >> 4;
            int cl = seg % 18, r = seg / 18;
            int y = iy - 1 + r, col = n0 + cl;
            unsigned int v = 0;
            if (y >= 0 && y < 56 && col < 58)
                v = xs[(((size_t)(b*2+g)*56 + y)*58 + col)*16 + ic2];
            tl[idx] = v;
        }
    }
    __syncthreads();

    int nlo = lane & 15, khi = lane >> 4;
    f32x4_t acc[5];
#pragma unroll
    for (int mt = 0; mt < 5; ++mt) acc[mt] = (f32x4_t){0.f,0.f,0.f,0.f};

    const half8_t* wp8 = (const half8_t*)Wp;
#pragma unroll
    for (int kt = 0; kt < 9; ++kt) {
        int ky = kt/3, kx = kt%3;
        half8_t bfrag = *(const half8_t*)&tile[wv][((ky*18) + nlo + kx)*32 + khi*8];
#pragma unroll
        for (int mt = 0; mt < 5; ++mt) {
            half8_t afrag = wp8[(((size_t)g*9 + kt)*5 + mt)*64 + lane];
            acc[mt] = __builtin_amdgcn_mfma_f32_16x16x32_f16(afrag, bfrag, acc[mt], 0, 0, 0);
        }
    }

    int pixcol = n0 + nlo;
    if (pixcol < 56) {
        int pix = iy*WW + pixcol;
#pragma unroll
        for (int mt = 0; mt < 5; ++mt) {
#pragma unroll
            for (int r = 0; r < 4; ++r) {
                int m = mt*16 + khi*4 + r;
                if (m < 74) {
                    float val = acc[mt][r] + bb[g*80 + m];
                    if (m < 49)
                        off3[((size_t)b*98 + g*49 + m)*HWA + pix] = val;
                    else
                        off2[((size_t)b*50 + g*25 + (m-49))*HWA + pix] = val;
                }
            }
        }
    }
}

// ---------- 3. deform: 16 px/block, 4 px/wave; single-address pair gather ----------
// WP=true: write fp16 pair layout only (feeds deform2 + combine's o1 read).
// WP=false: write compact fp16 NHWC out.
template<int K, int KS, int PAD, bool WP>
__global__ __launch_bounds__(256)
void k_deform(const _Float16* __restrict__ xp, const float* __restrict__ off,
              const float* __restrict__ wg, const float* __restrict__ bias,
              _Float16* __restrict__ outh, float* __restrict__ partial,
              _Float16* __restrict__ xpo) {
    __shared__ float lw[K*65];          // [t][c] padded
    __shared__ float loffs[2*K][16];
    __shared__ int4  lmeta[16][K];      // {byte offset (c=0), 0, wA, wB}
    __shared__ float red[16][64];
    int tid = threadIdx.x + threadIdx.y*64;   // 256
    int blk = blockIdx.x;               // BB*HWA/16 = 784
    int xcd = blk & 7;                  // slab: (batch, image-half)
    int idx = blk >> 3;                 // 0..97
    int b   = xcd >> 1;
    int hw0 = (xcd & 1)*(HWA/2) + idx*16;

    for (int i = tid; i < K*64; i += 256) {
        int c = i / K, t = i % K;
        lw[t*65 + c] = wg[i];
    }
    for (int i = tid; i < 8*K; i += 256) {   // 2K rows x 4 float4
        int row = i >> 2, q4 = i & 3;
        float4 v = *(const float4*)&off[((size_t)b*2*K + row)*HWA + hw0 + q4*4];
        loffs[row][q4*4 + 0] = v.x; loffs[row][q4*4 + 1] = v.y;
        loffs[row][q4*4 + 2] = v.z; loffs[row][q4*4 + 3] = v.w;
    }
    __syncthreads();
    for (int i = tid; i < 16*K; i += 256) {  // lane-parallel bilinear meta
        int p = i / K, t = i % K;
        int hw = hw0 + p;
        int h = hw / WW, w = hw % WW;
        int ky = t / KS, kx = t % KS;
        float py = (float)(h - PAD + 3*ky) + loffs[2*t][p];
        float px = (float)(w - PAD + 3*kx) + loffs[2*t+1][p];
        float y0f = floorf(py), x0f = floorf(px);
        float ly = py - y0f, lx = px - x0f;
        float hy = 1.f - ly, hx = 1.f - lx;
        int y0 = (int)y0f, x0 = (int)x0f;
        int j = x0 + 1;
        bool jv = (j >= 0) && (j <= 56);
        int jc = jv ? j : 0;
        float s0 = ((y0   >= 0) && (y0   < HH) && jv) ? hy : 0.f;
        float s1 = ((y0+1 >= 0) && (y0+1 < HH) && jv) ? ly : 0.f;
        bool use1 = (s0 == 0.f);
        int rbase = use1 ? min(max(y0 + 1, 0), 55) : y0;   // always in [0,55]
        float aw = use1 ? s1 : s0;
        float bw = use1 ? 0.f : s1;
        int4 m;
        m.x = (rbase*57 + jc)*(64*4);   // byte offset of pair elem at c=0
        m.y = 0;
        __half2 wa = __floats2half2_rn(aw*hx, aw*lx);
        __half2 wb = __floats2half2_rn(bw*hx, bw*lx);
        m.z = *(int*)&wa;
        m.w = *(int*)&wb;
        lmeta[p][t] = m;
    }
    __syncthreads();

    int yp = threadIdx.y;               // wave handles pixels yp+4s, s=0..3
    int c  = threadIdx.x;
    const char* xc = (const char*)xp + (size_t)b*PSTRB + c*4;

    float acc[4] = {0.f, 0.f, 0.f, 0.f};
#pragma unroll 2
    for (int t = 0; t < K; ++t) {
        float lwv = lw[t*65 + c];
#pragma unroll
        for (int s = 0; s < 4; ++s) {
            int4 m = lmeta[yp + 4*s][t];
            h2_t r0 = *(const h2_t*)(xc + m.x);
            h2_t r1 = *(const h2_t*)(xc + m.x + ROWSTRB);
            float v = __builtin_amdgcn_fdot2(r0, *(h2_t*)&m.z, 0.f, false);
            v = __builtin_amdgcn_fdot2(r1, *(h2_t*)&m.w, v, false);
            acc[s] = fmaf(v, lwv, acc[s]);
        }
    }
    float bs = bias[c];
#pragma unroll
    for (int s = 0; s < 4; ++s) {
        float val = acc[s] + bs;
        int hw = hw0 + yp + 4*s;
        if (WP) {                       // pair halves (sole sink of branch-1 values)
            int y = hw / WW, w = hw % WW;
            _Float16* base = xpo + ((size_t)(b*PROWS + y)*57)*CC*2;
            _Float16 hv = (_Float16)val;
            base[((w    )*64 + c)*2 + 1] = hv;      // slot w hi
            base[((w + 1)*64 + c)*2 + 0] = hv;      // slot w+1 lo
            if (w == 0)  base[(c)*2 + 0] = (_Float16)0.f;
            if (w == 55) base[((56)*64 + c)*2 + 1] = (_Float16)0.f;
        } else {                        // compact fp16 NHWC
            outh[((size_t)b*HWA + hw)*CC + c] = (_Float16)val;
        }
        red[yp + 4*s][c] = val;
    }
    __syncthreads();
    if (yp == 0) {
        float s = 0.f;
#pragma unroll
        for (int r = 0; r < 16; ++r) s += red[r][c];
        partial[((size_t)b*(HWA/16) + (hw0 >> 4))*64 + c] = s;
    }
}

// ---------- 4. softmax gate + combine (full GAP reduction in prologue) ----------
// o1 values come from xp2 pair hi-halves; o2 from compact fp16 NHWC.
__global__ void k_combine(const _Float16* __restrict__ xp2, const _Float16* __restrict__ o2h,
                          const float* __restrict__ p1, const float* __restrict__ p2,
                          float* __restrict__ out) {
    __shared__ float tile[64][65];
    __shared__ float gsh[2][64];
    int blk = blockIdx.x;              // BB * (HWA/64) = 196
    int b   = blk / (HWA/64);
    int t0  = (blk % (HWA/64)) * 64;
    int tid = threadIdx.x;             // 256
    int c = tid & 63, q = tid >> 6;

    if (tid < 128) {
        int f = tid >> 6, cc = tid & 63;
        const float* p = f ? p2 : p1;
        float s = 0.f;
        for (int j = 0; j < HWA/16; ++j)
            s += p[((size_t)b*(HWA/16) + j)*64 + cc];   // 196 independent L2 loads
        gsh[f][cc] = s * (1.f/HWA);
    }
    __syncthreads();

    float g1v = gsh[0][c];
    float g2v = gsh[1][c];
    float m  = fmaxf(g1v, g2v);
    float e1 = expf(g1v - m), e2 = expf(g2v - m);
    float a1 = e1 / (e1 + e2), a2 = 1.f - a1;

#pragma unroll
    for (int i = 0; i < 16; ++i) {
        int p = q + 4*i;
        int hw = t0 + p;
        int y = hw / WW, w = hw % WW;
        // o1 = hi half of xp2 slot (y, w)
        _Float16 h1 = xp2[(((size_t)(b*PROWS + y)*57 + w)*CC + c)*2 + 1];
        _Float16 h2v = o2h[((size_t)b*HWA + hw)*CC + c];
        tile[p][c] = (float)h1*a1 + (float)h2v*a2;
    }
    __syncthreads();
    int p2i = tid & 63;
#pragma unroll
    for (int i = 0; i < 16; ++i) {
        int c2 = q + 4*i;
        out[((size_t)b*CC + c2)*HWA + t0 + p2i] = tile[p2i][c2];
    }
}

extern "C" void kernel_launch(void* const* d_in, const int* in_sizes, int n_in,
                              void* d_out, int out_size, void* d_ws, size_t ws_size,
                              hipStream_t stream) {
    const float* x      = (const float*)d_in[0];
    const float* w_off3 = (const float*)d_in[1];
    const float* b_off3 = (const float*)d_in[2];
    const float* w_off2 = (const float*)d_in[3];
    const float* b_off2 = (const float*)d_in[4];
    const float* w7     = (const float*)d_in[5];
    const float* b7     = (const float*)d_in[6];
    const float* w5     = (const float*)d_in[7];
    const float* b5     = (const float*)d_in[8];
    float* out = (float*)d_out;

    const size_t PAIRF = (size_t)BB*PROWS*57*64;   // 831744 floats
    float* ws    = (float*)d_ws;
    float* off3r = ws;                    // 1229312
    float* off2r = off3r + 1229312;       // 627200
    float* xp1f  = off2r + 627200;        // 831744
    float* xp2f  = xp1f  + PAIRF;         // 831744
    float* xhf   = xp2f  + PAIRF;         // 415744 (831488 fp16)
    float* o2hf  = xhf   + 415744;        // 401408 (802816 fp16)
    float* part1 = o2hf  + 401408;        // 50176 (b*196*64)
    float* part2 = part1 + 50176;         // 50176
    float* wpf   = part2 + 50176;         // 23040 (46080 fp16)
    float* bbp   = wpf   + 23040;         // 160
    __half2*  xp1 = (__half2*)xp1f;
    _Float16* xp2h = (_Float16*)xp2f;
    _Float16* xh  = (_Float16*)xhf;
    _Float16* o2h = (_Float16*)o2hf;
    _Float16* Wp  = (_Float16*)wpf;
    size_t need = (size_t)(1229312 + 627200 + 831744*2 + 415744 + 401408
                           + 50176*2 + 23040 + 160) * 4;
    if (ws_size < need) return;

    // 1: fused prep (pair layout + conv fp16 layout + weight pack)
    k_prep<<<BB*56 + 181, 256, 0, stream>>>(x, w_off3, w_off2, b_off3, b_off2,
                                            xp1, xh, Wp, bbp);
    // 2: both grouped convs via MFMA
    k_convmfma<<<BB*2*56, dim3(64,4), 0, stream>>>(xh, Wp, bbp, off3r, off2r);
    // 3: deform1 (16 px/block; writes xp2 pairs + gap partials; no fp32 out)
    k_deform<49,7,9,true><<<BB*(HWA/16), dim3(64,4), 0, stream>>>(
        (const _Float16*)xp1, off3r, w7, b7, nullptr, part1, xp2h);
    // 4: deform2 (writes compact fp16 out2 + gap partials)
    k_deform<25,5,6,false><<<BB*(HWA/16), dim3(64,4), 0, stream>>>(
        xp2h, off2r, w5, b5, o2h, part2, nullptr);
    // 5: combine (full GAP reduction, softmax gate, NHWC->NCHW)
    k_combine<<<BB*(HWA/64), 256, 0, stream>>>(xp2h, o2h, part1, part2, out);
}

// Round 20
// 149.184 us; speedup vs baseline: 1.0167x; 1.0167x over previous
//
#include <hip/hip_runtime.h>
#include <hip/hip_fp16.h>
#include <math.h>

#define HH 56
#define WW 56
#define CC 64
#define BB 4
#define HWA (HH*WW)   // 3136

typedef _Float16 half8_t __attribute__((ext_vector_type(8)));
typedef _Float16 h2_t   __attribute__((ext_vector_type(2)));
typedef float f32x4_t __attribute__((ext_vector_type(4)));

// pair layout (padded): xp[b][y 0..56][j 0..56][c] = {v(y,j-1), v(y,j)} fp16.
// Row 56 is never written (poison = finite fp16); reads of it always carry 0 weight.
#define PROWS 57
#define PSTRB (PROWS*57*64*4)    // bytes per batch
#define ROWSTRB (57*64*4)        // bytes per row

// ---------- 1. fused prep: pair rows + conv fp16 layout + weight pack ----------
__global__ __launch_bounds__(256)
void k_prep(const float* __restrict__ x,
            const float* __restrict__ w3, const float* __restrict__ w2,
            const float* __restrict__ b3, const float* __restrict__ b2,
            __half2* __restrict__ xp, _Float16* __restrict__ xh,
            _Float16* __restrict__ Wp, float* __restrict__ bbp) {
    int blk = blockIdx.x;
    int tid = threadIdx.x;
    if (blk < BB*56) {
        __shared__ float ld[64*57];        // [c][xcol] pad 57
        int b = blk / 56, y = blk % 56;
        for (int i = tid; i < 64*56; i += 256) {
            int c = i / 56, col = i % 56;
            ld[c*57 + col] = x[((size_t)b*CC + c)*HWA + y*WW + col];
        }
        __syncthreads();
        for (int i = tid; i < 57*64; i += 256) {
            int j = i >> 6, c = i & 63;
            float lo = (j > 0)  ? ld[c*57 + j - 1] : 0.f;
            float hi = (j < 56) ? ld[c*57 + j]     : 0.f;
            xp[((size_t)(b*PROWS + y)*57 + j)*CC + c] = __floats2half2_rn(lo, hi);
        }
        _Float16* dst = xh + (((size_t)(b*2)*56 + y)*58)*32;
        for (int i = tid; i < 2*58*32; i += 256) {
            int g = i / 1856;
            int r = i % 1856;
            int col = r / 32, ic = r % 32;
            float v = 0.f;
            if (col >= 1 && col <= 56) v = ld[(g*32 + ic)*57 + col - 1];
            dst[(size_t)g*56*58*32 + r] = (_Float16)v;
        }
    } else {
        int i = (blk - BB*56)*256 + tid;
        if (i < 46080) {
            int j    = i & 7;
            int lane = (i >> 3) & 63;
            int mt   = (i >> 9) % 5;
            int kt   = (i / 2560) % 9;
            int g    = i / 23040;
            int m  = mt*16 + (lane & 15);
            int ic = (lane >> 4)*8 + j;
            int ky = kt/3, kx = kt%3;
            float v = 0.f;
            if (m < 49)      v = w3[((g*49 + m)*32 + ic)*9 + ky*3 + kx];
            else if (m < 74) v = w2[((g*25 + (m-49))*32 + ic)*9 + ky*3 + kx];
            Wp[i] = (_Float16)v;
        } else if (i < 46240) {
            int t = i - 46080; int g = t/80, m = t%80;
            float v = 0.f;
            if (m < 49)      v = b3[g*49 + m];
            else if (m < 74) v = b2[g*25 + (m-49)];
            bbp[t] = v;
        }
    }
}

// ---------- 2. MFMA conv: 4 waves/block, one 16-pixel tile per wave ----------
__global__ __launch_bounds__(256)
void k_convmfma(const _Float16* __restrict__ xh, const _Float16* __restrict__ Wp,
                const float* __restrict__ bb,
                float* __restrict__ off3, float* __restrict__ off2) {
    __shared__ _Float16 tile[4][3*18*32];   // 13824 B
    int blk = blockIdx.x;                   // 448
    int iy = blk % 56;
    int g  = (blk / 56) & 1;
    int b  = blk / 112;
    int wv   = threadIdx.y;                 // 0..3 = nq
    int lane = threadIdx.x;
    int n0 = wv * 16;

    const unsigned int* xs = (const unsigned int*)xh;
    unsigned int* tl = (unsigned int*)&tile[wv][0];
#pragma unroll
    for (int i = 0; i < 14; ++i) {
        int idx = i*64 + lane;              // 864 uints
        if (idx < 864) {
            int ic2 = idx & 15;
            int seg = idx >> 4;
            int cl = seg % 18, r = seg / 18;
            int y = iy - 1 + r, col = n0 + cl;
            unsigned int v = 0;
            if (y >= 0 && y < 56 && col < 58)
                v = xs[(((size_t)(b*2+g)*56 + y)*58 + col)*16 + ic2];
            tl[idx] = v;
        }
    }
    __syncthreads();

    int nlo = lane & 15, khi = lane >> 4;
    f32x4_t acc[5];
#pragma unroll
    for (int mt = 0; mt < 5; ++mt) acc[mt] = (f32x4_t){0.f,0.f,0.f,0.f};

    const half8_t* wp8 = (const half8_t*)Wp;
#pragma unroll
    for (int kt = 0; kt < 9; ++kt) {
        int ky = kt/3, kx = kt%3;
        half8_t bfrag = *(const half8_t*)&tile[wv][((ky*18) + nlo + kx)*32 + khi*8];
#pragma unroll
        for (int mt = 0; mt < 5; ++mt) {
            half8_t afrag = wp8[(((size_t)g*9 + kt)*5 + mt)*64 + lane];
            acc[mt] = __builtin_amdgcn_mfma_f32_16x16x32_f16(afrag, bfrag, acc[mt], 0, 0, 0);
        }
    }

    int pixcol = n0 + nlo;
    if (pixcol < 56) {
        int pix = iy*WW + pixcol;
#pragma unroll
        for (int mt = 0; mt < 5; ++mt) {
#pragma unroll
            for (int r = 0; r < 4; ++r) {
                int m = mt*16 + khi*4 + r;
                if (m < 74) {
                    float val = acc[mt][r] + bb[g*80 + m];
                    if (m < 49)
                        off3[((size_t)b*98 + g*49 + m)*HWA + pix] = val;
                    else
                        off2[((size_t)b*50 + g*25 + (m-49))*HWA + pix] = val;
                }
            }
        }
    }
}

// ---------- 3. deform: 8 px/block, 2 px/wave; single-address pair gather ----------
template<int K, int KS, int PAD, bool WP>
__global__ __launch_bounds__(256)
void k_deform(const _Float16* __restrict__ xp, const float* __restrict__ off,
              const float* __restrict__ wg, const float* __restrict__ bias,
              float* __restrict__ out, float* __restrict__ partial,
              _Float16* __restrict__ xpo) {
    __shared__ float lw[K*65];          // [t][c] padded
    __shared__ float loffs[2*K][8];
    __shared__ int4  lmeta[8][K];       // {byte offset (c=0), 0, wA, wB}
    __shared__ float red[8][64];
    int tid = threadIdx.x + threadIdx.y*64;   // 256
    int blk = blockIdx.x;               // BB*HWA/8 = 1568
    int xcd = blk & 7;                  // slab: (batch, image-half)
    int idx = blk >> 3;                 // 0..195
    int b   = xcd >> 1;
    int hw0 = (xcd & 1)*(HWA/2) + idx*8;

    for (int i = tid; i < K*64; i += 256) {
        int c = i / K, t = i % K;
        lw[t*65 + c] = wg[i];
    }
    for (int i = tid; i < 4*K; i += 256) {   // 2K rows x 2 float4
        int row = i >> 1, half = i & 1;
        float4 v = *(const float4*)&off[((size_t)b*2*K + row)*HWA + hw0 + half*4];
        loffs[row][half*4 + 0] = v.x; loffs[row][half*4 + 1] = v.y;
        loffs[row][half*4 + 2] = v.z; loffs[row][half*4 + 3] = v.w;
    }
    __syncthreads();
    for (int i = tid; i < 8*K; i += 256) {   // lane-parallel bilinear meta
        int p = i / K, t = i % K;
        int hw = hw0 + p;
        int h = hw / WW, w = hw % WW;
        int ky = t / KS, kx = t % KS;
        float py = (float)(h - PAD + 3*ky) + loffs[2*t][p];
        float px = (float)(w - PAD + 3*kx) + loffs[2*t+1][p];
        float y0f = floorf(py), x0f = floorf(px);
        float ly = py - y0f, lx = px - x0f;
        float hy = 1.f - ly, hx = 1.f - lx;
        int y0 = (int)y0f, x0 = (int)x0f;
        int j = x0 + 1;
        bool jv = (j >= 0) && (j <= 56);
        int jc = jv ? j : 0;
        float s0 = ((y0   >= 0) && (y0   < HH) && jv) ? hy : 0.f;
        float s1 = ((y0+1 >= 0) && (y0+1 < HH) && jv) ? ly : 0.f;
        bool use1 = (s0 == 0.f);
        int rbase = use1 ? min(max(y0 + 1, 0), 55) : y0;   // always in [0,55]
        float aw = use1 ? s1 : s0;
        float bw = use1 ? 0.f : s1;
        int4 m;
        m.x = (rbase*57 + jc)*(64*4);   // byte offset of pair elem at c=0
        m.y = 0;
        __half2 wa = __floats2half2_rn(aw*hx, aw*lx);
        __half2 wb = __floats2half2_rn(bw*hx, bw*lx);
        m.z = *(int*)&wa;
        m.w = *(int*)&wb;
        lmeta[p][t] = m;
    }
    __syncthreads();

    int yp = threadIdx.y;               // wave handles pixels yp and yp+4
    int c  = threadIdx.x;
    const char* xc = (const char*)xp + (size_t)b*PSTRB + c*4;

    float acc0 = 0.f, acc1 = 0.f;
#pragma unroll 2
    for (int t = 0; t < K; ++t) {
        int4 m0 = lmeta[yp][t];
        int4 m1 = lmeta[yp + 4][t];
        h2_t r0a = *(const h2_t*)(xc + m0.x);
        h2_t r1a = *(const h2_t*)(xc + m0.x + ROWSTRB);
        h2_t r0b = *(const h2_t*)(xc + m1.x);
        h2_t r1b = *(const h2_t*)(xc + m1.x + ROWSTRB);
        float lwv = lw[t*65 + c];
        float v0 = __builtin_amdgcn_fdot2(r0a, *(h2_t*)&m0.z, 0.f, false);
        v0 = __builtin_amdgcn_fdot2(r1a, *(h2_t*)&m0.w, v0, false);
        float v1 = __builtin_amdgcn_fdot2(r0b, *(h2_t*)&m1.z, 0.f, false);
        v1 = __builtin_amdgcn_fdot2(r1b, *(h2_t*)&m1.w, v1, false);
        acc0 = fmaf(v0, lwv, acc0);
        acc1 = fmaf(v1, lwv, acc1);
    }
    float bs = bias[c];
    float val0 = acc0 + bs;
    float val1 = acc1 + bs;
    int hwA = hw0 + yp, hwB = hw0 + yp + 4;
    out[((size_t)b*HWA + hwA)*CC + c] = val0;
    out[((size_t)b*HWA + hwB)*CC + c] = val1;

    if (WP) {                           // pair halves for the next deform's source
#pragma unroll
        for (int s = 0; s < 2; ++s) {
            int hw = s ? hwB : hwA;
            float val = s ? val1 : val0;
            int y = hw / WW, w = hw % WW;
            _Float16* base = xpo + ((size_t)(b*PROWS + y)*57)*CC*2;
            _Float16 hv = (_Float16)val;
            base[((w    )*64 + c)*2 + 1] = hv;      // slot w hi
            base[((w + 1)*64 + c)*2 + 0] = hv;      // slot w+1 lo
            if (w == 0)  base[(c)*2 + 0] = (_Float16)0.f;
            if (w == 55) base[((56)*64 + c)*2 + 1] = (_Float16)0.f;
        }
    }

    red[yp][c] = val0;
    red[yp + 4][c] = val1;
    __syncthreads();
    if (yp == 0) {
        float s = red[0][c] + red[1][c] + red[2][c] + red[3][c]
                + red[4][c] + red[5][c] + red[6][c] + red[7][c];
        partial[((size_t)b*(HWA/8) + (hw0 >> 3))*64 + c] = s;
    }
}

// ---------- 4. GAP stage A: 112 blocks, 28 partial rows each ----------
__global__ void k_gapA(const float* __restrict__ p1, const float* __restrict__ p2,
                       float* __restrict__ g2) {
    __shared__ float red[4][64];
    int blk = blockIdx.x;              // 8bf * 14chunk
    int chunk = blk % 14;
    int bf    = blk / 14;
    int b     = bf >> 1;
    const float* p = (bf & 1) ? p2 : p1;
    int tid = threadIdx.x;             // 256
    int c = tid & 63, s = tid >> 6;
    float sum = 0.f;
#pragma unroll
    for (int i = 0; i < 7; ++i) {
        int j = chunk*28 + s + 4*i;
        sum += p[((size_t)b*(HWA/8) + j)*64 + c];
    }
    red[s][c] = sum;
    __syncthreads();
    if (s == 0)
        g2[((size_t)bf*14 + chunk)*64 + c]
            = red[0][c] + red[1][c] + red[2][c] + red[3][c];
}

// ---------- 5. softmax gate + combine (finishes GAP in prologue) ----------
__global__ void k_combine(const float* __restrict__ o1, const float* __restrict__ o2,
                          const float* __restrict__ g2, float* __restrict__ out) {
    __shared__ float tile[64][65];
    __shared__ float gsh[2][64];
    int blk = blockIdx.x;              // BB * (HWA/64)
    int b   = blk / (HWA/64);
    int t0  = (blk % (HWA/64)) * 64;
    int tid = threadIdx.x;             // 256
    int c = tid & 63, q = tid >> 6;

    if (tid < 128) {
        int f = tid >> 6, cc = tid & 63;
        float s = 0.f;
#pragma unroll
        for (int k = 0; k < 14; ++k)
            s += g2[((size_t)(b*2+f)*14 + k)*64 + cc];
        gsh[f][cc] = s * (1.f/HWA);
    }
    __syncthreads();

    float g1v = gsh[0][c];
    float g2v = gsh[1][c];
    float m  = fmaxf(g1v, g2v);
    float e1 = expf(g1v - m), e2 = expf(g2v - m);
    float a1 = e1 / (e1 + e2), a2 = 1.f - a1;

#pragma unroll
    for (int i = 0; i < 16; ++i) {
        int p = q + 4*i;
        size_t idx = ((size_t)b*HWA + t0 + p)*CC + c;
        tile[p][c] = o1[idx]*a1 + o2[idx]*a2;
    }
    __syncthreads();
    int p2 = tid & 63;
#pragma unroll
    for (int i = 0; i < 16; ++i) {
        int c2 = q + 4*i;
        out[((size_t)b*CC + c2)*HWA + t0 + p2] = tile[p2][c2];
    }
}

extern "C" void kernel_launch(void* const* d_in, const int* in_sizes, int n_in,
                              void* d_out, int out_size, void* d_ws, size_t ws_size,
                              hipStream_t stream) {
    const float* x      = (const float*)d_in[0];
    const float* w_off3 = (const float*)d_in[1];
    const float* b_off3 = (const float*)d_in[2];
    const float* w_off2 = (const float*)d_in[3];
    const float* b_off2 = (const float*)d_in[4];
    const float* w7     = (const float*)d_in[5];
    const float* b7     = (const float*)d_in[6];
    const float* w5     = (const float*)d_in[7];
    const float* b5     = (const float*)d_in[8];
    float* out = (float*)d_out;

    const size_t PAIRF = (size_t)BB*PROWS*57*64;
    float* ws    = (float*)d_ws;
    float* off3r = ws;                    // 1229312
    float* off2r = off3r + 1229312;       // 627200
    float* out1  = off2r + 627200;        // 802816
    float* out2  = out1  + 802816;        // 802816
    float* xp1f  = out2  + 802816;        // 831744
    float* xp2f  = xp1f  + PAIRF;         // 831744
    float* xhf   = xp2f  + PAIRF;         // 415744 (831488 fp16)
    float* part1 = xhf   + 415744;        // 100352 (b*392*64)
    float* part2 = part1 + 100352;        // 100352
    float* gpA   = part2 + 100352;        // 7168
    float* wpf   = gpA   + 7168;          // 23040 (46080 fp16)
    float* bbp   = wpf   + 23040;         // 160
    __half2*  xp1 = (__half2*)xp1f;
    _Float16* xp2h = (_Float16*)xp2f;
    _Float16* xh  = (_Float16*)xhf;
    _Float16* Wp  = (_Float16*)wpf;
    size_t need = (size_t)(1229312 + 627200 + 802816*2 + 831744*2 + 415744
                           + 100352*2 + 7168 + 23040 + 160) * 4;
    if (ws_size < need) return;

    // 1: fused prep (pair layout + conv fp16 layout + weight pack)
    k_prep<<<BB*56 + 181, 256, 0, stream>>>(x, w_off3, w_off2, b_off3, b_off2,
                                            xp1, xh, Wp, bbp);
    // 2: both grouped convs via MFMA
    k_convmfma<<<BB*2*56, dim3(64,4), 0, stream>>>(xh, Wp, bbp, off3r, off2r);
    // 3: deform1 (8 px/block; writes out1 + xp2 pairs + gap partials)
    k_deform<49,7,9,true><<<BB*(HWA/8), dim3(64,4), 0, stream>>>(
        (const _Float16*)xp1, off3r, w7, b7, out1, part1, xp2h);
    // 4: deform2
    k_deform<25,5,6,false><<<BB*(HWA/8), dim3(64,4), 0, stream>>>(
        xp2h, off2r, w5, b5, out2, part2, nullptr);
    // 5: GAP stage A
    k_gapA<<<8*14, 256, 0, stream>>>(part1, part2, gpA);
    // 6: combine (finishes GAP, softmax gate, NHWC->NCHW)
    k_combine<<<BB*(HWA/64), 256, 0, stream>>>(out1, out2, gpA, out);
}